// Round 11
// baseline (228.130 us; speedup 1.0000x reference)
//
#include <hip/hip_runtime.h>
#include <hip/hip_bf16.h>
#include <type_traits>

typedef __hip_bfloat16 bf16;
typedef __attribute__((ext_vector_type(8))) short bf16x8;
typedef __attribute__((ext_vector_type(4))) float f32x4;

#define N_LOC 4096

__device__ __forceinline__ bf16 to_bf16(float f) { return __float2bfloat16(f); }

// async global->LDS DMA, 16B per lane; LDS dest = wave-uniform base + lane*16
__device__ __forceinline__ void dma16(const bf16* g, bf16* l) {
  __builtin_amdgcn_global_load_lds((const __attribute__((address_space(1))) unsigned int*)g,
                                   (__attribute__((address_space(3))) unsigned int*)l, 16, 0, 0);
}

// ---------------- prep: fused {f32->bf16 convert of Q,K,V,Wo} + {W transpose-pack} ----------------
__global__ __launch_bounds__(256) void prep(const float* __restrict__ Q, const float* __restrict__ K,
                                            const float* __restrict__ V, const float* __restrict__ Wo,
                                            bf16* __restrict__ Qb, bf16* __restrict__ Kb,
                                            bf16* __restrict__ Vb, bf16* __restrict__ Wob,
                                            const float* __restrict__ Wq, const float* __restrict__ Wk,
                                            const float* __restrict__ Wv,
                                            bf16* __restrict__ oq, bf16* __restrict__ ok,
                                            bf16* __restrict__ ov) {
  __shared__ float tile[64][65];
  if (blockIdx.x < 3328) {
    long i = ((long)blockIdx.x * 256 + threadIdx.x) * 8;
    const float* src;
    bf16* dst;
    long off;
    if (i < 2097152)      { src = Q;  dst = Qb;  off = i; }
    else if (i < 4194304) { src = K;  dst = Kb;  off = i - 2097152; }
    else if (i < 6291456) { src = V;  dst = Vb;  off = i - 4194304; }
    else                  { src = Wo; dst = Wob; off = i - 6291456; }
    float4 a = *(const float4*)&src[off];
    float4 b = *(const float4*)&src[off + 4];
    union { bf16 h[8]; bf16x8 v; } u;
    u.h[0] = to_bf16(a.x); u.h[1] = to_bf16(a.y); u.h[2] = to_bf16(a.z); u.h[3] = to_bf16(a.w);
    u.h[4] = to_bf16(b.x); u.h[5] = to_bf16(b.y); u.h[6] = to_bf16(b.z); u.h[7] = to_bf16(b.w);
    *(bf16x8*)&dst[off] = u.v;
  } else {
    int pid = blockIdx.x - 3328;            // 0..383  (old dims: x 8, y 16, z 3)
    int z = pid >> 7;
    int rem = pid & 127;
    int xx = rem & 7, y = rem >> 3;
    const float* W = (z == 0) ? Wq : (z == 1) ? Wk : Wv;
    bf16* out = (z == 0) ? oq : (z == 1) ? ok : ov;
    int DH = (z == 2) ? 256 : 128;
    int nt = DH >> 6;
    if (y >= 4 * nt) return;
    int h = y / nt, tt = y - h * nt;
    int d0 = xx * 64, t0 = tt * 64;
    for (int i = threadIdx.x; i < 4096; i += 256) {
      int r = i >> 6, c = i & 63;
      tile[r][c] = W[((size_t)h * 512 + d0 + r) * DH + t0 + c];
    }
    __syncthreads();
    for (int i = threadIdx.x; i < 4096; i += 256) {
      int t = i >> 6, d = i & 63;
      out[((size_t)(h * DH + t0 + t)) * 512 + d0 + d] = to_bf16(tile[d][t]);
    }
  }
}

// ---------------- 128xBN GEMM body, double-buffered counted-vmcnt staging ----------------
// MODE 0: C bf16 [M][N]; MODE 1: C f32 [M][N]; MODE 2: C bf16 TRANSPOSED (vT[col][row], ld 4096)
// R11: MODE 0/1 epilogues now LDS-bounce + vectorized 16B stores (were 2B/4B scalar).
template <int BN, int MODE, typename OutT>
__device__ __forceinline__ void gemm_body(const bf16* __restrict__ A, const bf16* __restrict__ Bt,
                                          OutT* __restrict__ C, int N, int K, int m0, int n0,
                                          bf16* sm) {
  constexpr int WN = BN / 2, JN = WN / 16, NB = BN / 32;
  int tid = threadIdx.x, lane = tid & 63, w = tid >> 6;
  int quad = lane >> 4, l16 = lane & 15;
  int wm = (w >> 1) * 64, wn = (w & 1) * WN;
  int srow = lane >> 3;            // row-within-8-group staged by this lane
  int sG = (lane & 7) ^ srow;      // source granule for stored position lane&7

  bf16* Asb[2] = { sm, sm + 8192 };
  bf16* Bsb[2] = { sm + 16384, sm + 16384 + BN * 64 };

  const bf16* ga[4];
  const bf16* gb[NB];
#pragma unroll
  for (int j = 0; j < 4; j++) ga[j] = A + (long)(m0 + (4 * j + w) * 8 + srow) * K + sG * 8;
#pragma unroll
  for (int j = 0; j < NB; j++) gb[j] = Bt + (long)(n0 + (4 * j + w) * 8 + srow) * K + sG * 8;

  auto stage = [&](int b) {
#pragma unroll
    for (int j = 0; j < 4; j++) { dma16(ga[j], &Asb[b][(4 * j + w) * 512]); ga[j] += 64; }
#pragma unroll
    for (int j = 0; j < NB; j++) { dma16(gb[j], &Bsb[b][(4 * j + w) * 512]); gb[j] += 64; }
  };

  f32x4 acc[4][JN] = {};
  stage(0);
  asm volatile("" ::: "memory");
  int cur = 0;
  const int NK = K >> 6;
  for (int s = 0; s < NK; ++s) {
    if (s + 1 < NK) {
      stage(cur ^ 1);
      if constexpr (NB == 4) asm volatile("s_waitcnt vmcnt(8)" ::: "memory");
      else                   asm volatile("s_waitcnt vmcnt(6)" ::: "memory");
    } else {
      asm volatile("s_waitcnt vmcnt(0)" ::: "memory");
    }
    __builtin_amdgcn_s_barrier();      // tile s landed for all waves
    asm volatile("" ::: "memory");
    const bf16* Ac = Asb[cur];
    const bf16* Bc = Bsb[cur];
#pragma unroll
    for (int kk = 0; kk < 2; kk++) {
      bf16x8 af[4], bfr[JN];
#pragma unroll
      for (int i = 0; i < 4; i++) {
        int r = wm + i * 16 + l16;
        af[i] = *(const bf16x8*)&Ac[r * 64 + (((kk * 4 + quad) ^ r) & 7) * 8];
      }
#pragma unroll
      for (int j = 0; j < JN; j++) {
        int r = wn + j * 16 + l16;
        bfr[j] = *(const bf16x8*)&Bc[r * 64 + (((kk * 4 + quad) ^ r) & 7) * 8];
      }
#pragma unroll
      for (int i = 0; i < 4; i++)
#pragma unroll
        for (int j = 0; j < JN; j++)
          acc[i][j] = __builtin_amdgcn_mfma_f32_16x16x32_bf16(af[i], bfr[j], acc[i][j], 0, 0, 0);
    }
    asm volatile("" ::: "memory");
    __builtin_amdgcn_s_barrier();      // buf cur free for next stage's overwrite
    asm volatile("" ::: "memory");
    cur ^= 1;
  }

  if constexpr (MODE == 2) {
    bf16* tp = sm;  // [128][136] bf16 = 34.8 KB
#pragma unroll
    for (int i = 0; i < 4; i++)
#pragma unroll
      for (int j = 0; j < JN; j++)
#pragma unroll
        for (int r = 0; r < 4; r++)
          tp[(wn + j * 16 + l16) * 136 + wm + i * 16 + quad * 4 + r] = to_bf16(acc[i][j][r]);
    __syncthreads();
#pragma unroll
    for (int it = 0; it < 8; ++it) {
      int idx = it * 256 + tid;
      int rown = idx >> 4, c8 = (idx & 15) * 8;
      *(bf16x8*)&C[(size_t)(n0 + rown) * 4096 + m0 + c8] = *(const bf16x8*)&tp[rown * 136 + c8];
    }
  } else if constexpr (MODE == 0) {
    // row-major bounce: [128][BN+8] bf16, then coalesced bf16x8 stores (BN=128)
    bf16* tp = sm;  // [128][136] = 34.8 KB
#pragma unroll
    for (int i = 0; i < 4; i++)
#pragma unroll
      for (int j = 0; j < JN; j++)
#pragma unroll
        for (int r = 0; r < 4; r++)
          tp[(wm + i * 16 + quad * 4 + r) * 136 + wn + j * 16 + l16] = to_bf16(acc[i][j][r]);
    __syncthreads();
#pragma unroll
    for (int it = 0; it < 8; ++it) {
      int idx = it * 256 + tid;
      int rown = idx >> 4, c8 = (idx & 15) * 8;   // 16 thr/row x 8 elems = 128 cols
      *(bf16x8*)&C[(size_t)(m0 + rown) * N + n0 + c8] = *(const bf16x8*)&tp[rown * 136 + c8];
    }
  } else {
    // MODE 1: f32 bounce [128][68] (16B-aligned rows), float4 stores (BN=64)
    float* tpf = (float*)sm;  // 128*68*4 = 34.8 KB
#pragma unroll
    for (int i = 0; i < 4; i++)
#pragma unroll
      for (int j = 0; j < JN; j++)
#pragma unroll
        for (int r = 0; r < 4; r++)
          tpf[(wm + i * 16 + quad * 4 + r) * 68 + wn + j * 16 + l16] = acc[i][j][r];
    __syncthreads();
#pragma unroll
    for (int it = 0; it < 8; ++it) {
      int idx = it * 256 + tid;
      int rown = idx >> 4, c4 = (idx & 15) * 4;   // 16 thr/row x 4 f32 = 64 cols
      *(float4*)&((float*)C)[(size_t)(m0 + rown) * N + n0 + c4] =
          *(const float4*)&tpf[rown * 68 + c4];
    }
  }
}

// merged q/k/v projections, exact 512-block grid; z==2 writes vT directly (transposed epilogue)
__global__ __launch_bounds__(256) void proj_gemm(const bf16* __restrict__ QKVb,
                                                 const bf16* __restrict__ Wt,
                                                 bf16* __restrict__ qkout,
                                                 bf16* __restrict__ vTout) {
  __shared__ __align__(16) bf16 sm[4 * 128 * 64];   // 64 KB
  int bid = blockIdx.x;
  if (bid < 256) {
    int z = bid >> 7;                 // 0:q 1:k
    int t = bid & 127;
    int m0 = (t & 31) * 128, n0 = (t >> 5) * 128;
    gemm_body<128, 0, bf16>(QKVb + (size_t)z * 2097152, Wt + (size_t)z * 262144,
                            qkout + (size_t)z * 2097152, 512, 512, m0, n0, sm);
  } else {
    int t = bid - 256;                // 0..255 -> v projection, 4096x1024
    int m0 = (t & 31) * 128, n0 = (t >> 5) * 128;
    gemm_body<128, 2, bf16>(QKVb + (size_t)2 * 2097152, Wt + (size_t)2 * 262144,
                            vTout, 1024, 512, m0, n0, sm);
  }
}

// output projection: 128x64 tiles -> 256 blocks
__global__ __launch_bounds__(256) void out_gemm(const bf16* __restrict__ xin,
                                                const bf16* __restrict__ Wob,
                                                float* __restrict__ outp) {
  __shared__ __align__(16) bf16 sm[2 * 128 * 64 + 2 * 64 * 64];   // 48 KB
  gemm_body<64, 1, float>(xin, Wob, outp, 512, 1024, blockIdx.x * 128, blockIdx.y * 64, sm);
}

// ---------------- fused attention (R11: R10 + setprio around merged MFMA + exp2 fold) ----------------
// qb,kb: [N][512]; vT: [1024][N]; x: [N][1024]
// Block = (head, dvh, q0): 64 q x 128 dv; 8 waves (cd,g); grid 512 = 2 blocks/CU (73.5 KB LDS).
// S runs one tile ahead; per iter: {pf(t)->regs; barrier; stage K(t+2),V(t+1); counted
// vmcnt; setprio(1) [S(t+1) || PV(t)] setprio(0); exp2+pt-write; barrier}.
__global__ __launch_bounds__(512, 4) void attn(const bf16* __restrict__ qb,
                                               const bf16* __restrict__ kb,
                                               const bf16* __restrict__ vT,
                                               bf16* __restrict__ x) {
  __shared__ __align__(16) bf16 kt[2][64 * 128];   // [key][dk] swizzled, 2x16 KB
  __shared__ __align__(16) bf16 vt[2][128 * 64];   // [dv-half][key] swizzled, 2x16 KB
  __shared__ __align__(16) bf16 pt[64 * 72];       // [q][key], padded (9 KB)
  __shared__ float Lrow[64];

  const int bid = blockIdx.x;                      // 512 blocks
  const int xcd = bid & 7;
  const int head = xcd & 3;                        // one (head,dvh) pair per XCD
  const int dvh = xcd >> 2;                        // dv half 0..1
  const int q0 = (bid >> 3) * 64;                  // 0..4032
  const int tid = threadIdx.x;
  const int lane = tid & 63, w = tid >> 6;
  const int quad = lane >> 4, l16 = lane & 15;
  const int cd = w & 3;   // S: 16-key col tile; PV: 32-dv group
  const int g = w >> 2;   // q half

  // all-ones B-fragment: B[n][k] = (n==0) -> D[q][0] = sum_k P[q][k]
  bf16x8 onesf;
  {
    union { bf16 h[8]; bf16x8 v; } u;
    bf16 one = to_bf16(1.0f), zero = to_bf16(0.0f);
#pragma unroll
    for (int j = 0; j < 8; j++) u.h[j] = (l16 == 0) ? one : zero;
    onesf = u.v;
  }

  // preload q fragments (A-layout: m=l16, k=quad*8+j)
  bf16x8 qf[2][4];
#pragma unroll
  for (int i = 0; i < 2; i++) {
    const bf16* qrow = &qb[(size_t)(q0 + g * 32 + i * 16 + l16) * 512 + head * 128];
#pragma unroll
    for (int kk = 0; kk < 4; kk++) qf[i][kk] = *(const bf16x8*)&qrow[kk * 32 + quad * 8];
  }

  f32x4 oacc[2][2] = {};
  f32x4 oL[2] = {};
  const float S2 = (1.0f / 64.0f) * 1.44269504f;   // scale * log2(e): exp(x/64)=exp2(x*S2)

  // DMA source pointers (advance per staged tile). kt: 16 j-groups (4 key-rows x 128 dk);
  // vt: 16 j-groups (8 dv-rows x 64 keys). j = 2w+t2.
  const int j0 = 2 * w, j1 = 2 * w + 1;
  const bf16 *kp0, *kp1, *vp0, *vp1;
  {
    int r0 = 4 * j0 + (lane >> 4), r1 = 4 * j1 + (lane >> 4);
    int p = lane & 15;
    int G0 = (p & 8) | ((p ^ r0) & 7), G1 = (p & 8) | ((p ^ r1) & 7);
    kp0 = kb + (size_t)r0 * 512 + head * 128 + G0 * 8;
    kp1 = kb + (size_t)r1 * 512 + head * 128 + G1 * 8;
  }
  {
    int r0 = 8 * j0 + (lane >> 3), r1 = 8 * j1 + (lane >> 3);
    int p = lane & 7;
    int G0 = (p ^ r0) & 7, G1 = (p ^ r1) & 7;
    vp0 = vT + (size_t)(head * 256 + dvh * 128 + r0) * 4096 + G0 * 8;
    vp1 = vT + (size_t)(head * 256 + dvh * 128 + r1) * 4096 + G1 * 8;
  }

#define STAGE_K(b)                                      \
  do {                                                  \
    dma16(kp0, &kt[b][j0 * 512]);                       \
    dma16(kp1, &kt[b][j1 * 512]);                       \
    kp0 += 64 * 512; kp1 += 64 * 512;                   \
  } while (0)
#define STAGE_V(b)                                      \
  do {                                                  \
    dma16(vp0, &vt[b][j0 * 512]);                       \
    dma16(vp1, &vt[b][j1 * 512]);                       \
    vp0 += 64; vp1 += 64;                               \
  } while (0)

  // ---- prologue: stage K(0),V(0),K(1); compute S(0) -> pt ----
  STAGE_K(0);
  STAGE_V(0);
  STAGE_K(1);
  asm volatile("s_waitcnt vmcnt(2)" ::: "memory");   // K(0), V(0) landed; K(1) in flight
  __builtin_amdgcn_s_barrier();
  asm volatile("" ::: "memory");
  {
    const bf16* ktc = kt[0];
    f32x4 sacc[2] = {};
#pragma unroll
    for (int kk = 0; kk < 4; kk++) {
      int R = cd * 16 + l16;
      int G = kk * 4 + quad;
      bf16x8 kf = *(const bf16x8*)&ktc[R * 128 + (((G ^ R) & 7) | (G & 8)) * 8];
      sacc[0] = __builtin_amdgcn_mfma_f32_16x16x32_bf16(qf[0][kk], kf, sacc[0], 0, 0, 0);
      sacc[1] = __builtin_amdgcn_mfma_f32_16x16x32_bf16(qf[1][kk], kf, sacc[1], 0, 0, 0);
    }
#pragma unroll
    for (int i = 0; i < 2; i++)
#pragma unroll
      for (int r = 0; r < 4; r++)
        pt[(g * 32 + i * 16 + quad * 4 + r) * 72 + cd * 16 + l16] =
            to_bf16(exp2f(sacc[i][r] * S2));
  }
  asm volatile("s_waitcnt lgkmcnt(0)" ::: "memory");
  __builtin_amdgcn_s_barrier();                      // pt(0) ready
  asm volatile("" ::: "memory");

  for (int t = 0; t < 64; ++t) {
    // ---- load pf(t) into registers, then free pt for S(t+1) ----
    bf16x8 pf[2][2];
#pragma unroll
    for (int kk = 0; kk < 2; kk++)
#pragma unroll
      for (int i = 0; i < 2; i++)
        pf[kk][i] = *(const bf16x8*)&pt[(g * 32 + i * 16 + l16) * 72 + kk * 32 + quad * 8];
    asm volatile("s_waitcnt lgkmcnt(0)" ::: "memory");
    __builtin_amdgcn_s_barrier();        // all waves hold pf(t); pt free
    asm volatile("" ::: "memory");

    // ---- stage ahead: K(t+2) into buf t%2, V(t+1) into buf (t+1)%2 ----
    if (t < 62) STAGE_K(t & 1);
    if (t < 63) STAGE_V((t + 1) & 1);
    if (t < 62)      asm volatile("s_waitcnt vmcnt(4)" ::: "memory");  // K(t+1),V(t) landed
    else if (t == 62) asm volatile("s_waitcnt vmcnt(2)" ::: "memory");
    else              asm volatile("s_waitcnt vmcnt(0)" ::: "memory");

    // ---- merged phase: S(t+1) || PV(t), setprio around the MFMA cluster ----
    if (t < 63) {
      const bf16* ktc = kt[(t + 1) & 1];
      const bf16* vtc = vt[t & 1];
      f32x4 sacc[2] = {};
      __builtin_amdgcn_s_setprio(1);
#pragma unroll
      for (int kk = 0; kk < 4; kk++) {
        int R = cd * 16 + l16;
        int G = kk * 4 + quad;
        bf16x8 kf = *(const bf16x8*)&ktc[R * 128 + (((G ^ R) & 7) | (G & 8)) * 8];
        sacc[0] = __builtin_amdgcn_mfma_f32_16x16x32_bf16(qf[0][kk], kf, sacc[0], 0, 0, 0);
        sacc[1] = __builtin_amdgcn_mfma_f32_16x16x32_bf16(qf[1][kk], kf, sacc[1], 0, 0, 0);
      }
#pragma unroll
      for (int kk = 0; kk < 2; kk++) {
#pragma unroll
        for (int c = 0; c < 2; c++) {
          int R = cd * 32 + c * 16 + l16;
          int G = kk * 4 + quad;
          bf16x8 vf = *(const bf16x8*)&vtc[R * 64 + ((G ^ R) & 7) * 8];
#pragma unroll
          for (int i = 0; i < 2; i++)
            oacc[i][c] = __builtin_amdgcn_mfma_f32_16x16x32_bf16(pf[kk][i], vf, oacc[i][c], 0, 0, 0);
        }
        if (cd == 3) {
#pragma unroll
          for (int i = 0; i < 2; i++)
            oL[i] = __builtin_amdgcn_mfma_f32_16x16x32_bf16(pf[kk][i], onesf, oL[i], 0, 0, 0);
        }
      }
      __builtin_amdgcn_s_setprio(0);
      // exp(t+1) + pt write (trails the MFMA cluster)
#pragma unroll
      for (int i = 0; i < 2; i++)
#pragma unroll
        for (int r = 0; r < 4; r++)
          pt[(g * 32 + i * 16 + quad * 4 + r) * 72 + cd * 16 + l16] =
              to_bf16(exp2f(sacc[i][r] * S2));
    } else {
      // last iter: PV(63) only
      const bf16* vtc = vt[t & 1];
      __builtin_amdgcn_s_setprio(1);
#pragma unroll
      for (int kk = 0; kk < 2; kk++) {
#pragma unroll
        for (int c = 0; c < 2; c++) {
          int R = cd * 32 + c * 16 + l16;
          int G = kk * 4 + quad;
          bf16x8 vf = *(const bf16x8*)&vtc[R * 64 + ((G ^ R) & 7) * 8];
#pragma unroll
          for (int i = 0; i < 2; i++)
            oacc[i][c] = __builtin_amdgcn_mfma_f32_16x16x32_bf16(pf[kk][i], vf, oacc[i][c], 0, 0, 0);
        }
        if (cd == 3) {
#pragma unroll
          for (int i = 0; i < 2; i++)
            oL[i] = __builtin_amdgcn_mfma_f32_16x16x32_bf16(pf[kk][i], onesf, oL[i], 0, 0, 0);
        }
      }
      __builtin_amdgcn_s_setprio(0);
    }
    asm volatile("s_waitcnt lgkmcnt(0)" ::: "memory");   // pt(t+1) writes visible
    __builtin_amdgcn_s_barrier();        // pt(t+1) ready; buffers rotate
    asm volatile("" ::: "memory");
  }
#undef STAGE_K
#undef STAGE_V

  // L at lanes l16==0 of cd==3 waves (C-layout col 0)
  if (cd == 3 && l16 == 0) {
#pragma unroll
    for (int i = 0; i < 2; i++)
#pragma unroll
      for (int r = 0; r < 4; r++) Lrow[g * 32 + i * 16 + quad * 4 + r] = oL[i][r];
  }
  __syncthreads();

  // normalize + write x[n][head*256 + dvh*128 + dv]
#pragma unroll
  for (int i = 0; i < 2; i++)
#pragma unroll
    for (int c = 0; c < 2; c++)
#pragma unroll
      for (int r = 0; r < 4; r++) {
        int row = g * 32 + i * 16 + quad * 4 + r;
        float v = oacc[i][c][r] / Lrow[row];
        x[(size_t)(q0 + row) * 1024 + head * 256 + dvh * 128 + cd * 32 + c * 16 + l16] =
            to_bf16(v);
      }
}

// ---------------- launch ----------------
extern "C" void kernel_launch(void* const* d_in, const int* in_sizes, int n_in,
                              void* d_out, int out_size, void* d_ws, size_t ws_size,
                              hipStream_t stream) {
  const float* Q  = (const float*)d_in[0];
  const float* Km = (const float*)d_in[1];
  const float* V  = (const float*)d_in[2];
  const float* Wq = (const float*)d_in[3];
  const float* Wk = (const float*)d_in[4];
  const float* Wv = (const float*)d_in[5];
  const float* Wo = (const float*)d_in[6];
  float* out = (float*)d_out;

  bf16* ws  = (bf16*)d_ws;
  bf16* Qb  = ws;                 // 4096x512   (Qb,Kb,Vb contiguous)
  bf16* Kb  = Qb + 2097152;
  bf16* Vb  = Kb + 2097152;
  bf16* Wqt = Vb + 2097152;       // 512x512  (Wqt,Wkt,Wvt contiguous)
  bf16* Wkt = Wqt + 262144;
  bf16* Wvt = Wkt + 262144;       // 1024x512 (Bt)
  bf16* Wob = Wvt + 524288;       // 512x1024 (Bt = Wo as-is)
  bf16* qb  = Wob + 524288;       // 4096x512   (qb,kb contiguous)
  bf16* kb  = qb + 2097152;
  bf16* vT  = kb + 2097152;       // 1024x4096  (written directly by proj z==2)
  bf16* x   = vT + 4194304;       // 4096x1024

  prep<<<3712, 256, 0, stream>>>(Q, Km, V, Wo, Qb, Kb, Vb, Wob, Wq, Wk, Wv, Wqt, Wkt, Wvt);

  proj_gemm<<<512, 256, 0, stream>>>(Qb, Wqt, qb, vT);

  attn<<<512, 512, 0, stream>>>(qb, kb, vT, x);

  out_gemm<<<dim3(32, 8), 256, 0, stream>>>(x, Wob, out);
}

// Round 12
// 217.162 us; speedup vs baseline: 1.0505x; 1.0505x over previous
//
#include <hip/hip_runtime.h>
#include <hip/hip_bf16.h>
#include <type_traits>

typedef __hip_bfloat16 bf16;
typedef __attribute__((ext_vector_type(8))) short bf16x8;
typedef __attribute__((ext_vector_type(4))) float f32x4;

#define N_LOC 4096

__device__ __forceinline__ bf16 to_bf16(float f) { return __float2bfloat16(f); }

// async global->LDS DMA, 16B per lane; LDS dest = wave-uniform base + lane*16
__device__ __forceinline__ void dma16(const bf16* g, bf16* l) {
  __builtin_amdgcn_global_load_lds((const __attribute__((address_space(1))) unsigned int*)g,
                                   (__attribute__((address_space(3))) unsigned int*)l, 16, 0, 0);
}

// ---------------- prep: fused {f32->bf16 convert of Q,K,V,Wo} + {W transpose-pack} ----------------
__global__ __launch_bounds__(256) void prep(const float* __restrict__ Q, const float* __restrict__ K,
                                            const float* __restrict__ V, const float* __restrict__ Wo,
                                            bf16* __restrict__ Qb, bf16* __restrict__ Kb,
                                            bf16* __restrict__ Vb, bf16* __restrict__ Wob,
                                            const float* __restrict__ Wq, const float* __restrict__ Wk,
                                            const float* __restrict__ Wv,
                                            bf16* __restrict__ oq, bf16* __restrict__ ok,
                                            bf16* __restrict__ ov) {
  __shared__ float tile[64][65];
  if (blockIdx.x < 3328) {
    long i = ((long)blockIdx.x * 256 + threadIdx.x) * 8;
    const float* src;
    bf16* dst;
    long off;
    if (i < 2097152)      { src = Q;  dst = Qb;  off = i; }
    else if (i < 4194304) { src = K;  dst = Kb;  off = i - 2097152; }
    else if (i < 6291456) { src = V;  dst = Vb;  off = i - 4194304; }
    else                  { src = Wo; dst = Wob; off = i - 6291456; }
    float4 a = *(const float4*)&src[off];
    float4 b = *(const float4*)&src[off + 4];
    union { bf16 h[8]; bf16x8 v; } u;
    u.h[0] = to_bf16(a.x); u.h[1] = to_bf16(a.y); u.h[2] = to_bf16(a.z); u.h[3] = to_bf16(a.w);
    u.h[4] = to_bf16(b.x); u.h[5] = to_bf16(b.y); u.h[6] = to_bf16(b.z); u.h[7] = to_bf16(b.w);
    *(bf16x8*)&dst[off] = u.v;
  } else {
    int pid = blockIdx.x - 3328;            // 0..383  (old dims: x 8, y 16, z 3)
    int z = pid >> 7;
    int rem = pid & 127;
    int xx = rem & 7, y = rem >> 3;
    const float* W = (z == 0) ? Wq : (z == 1) ? Wk : Wv;
    bf16* out = (z == 0) ? oq : (z == 1) ? ok : ov;
    int DH = (z == 2) ? 256 : 128;
    int nt = DH >> 6;
    if (y >= 4 * nt) return;
    int h = y / nt, tt = y - h * nt;
    int d0 = xx * 64, t0 = tt * 64;
    for (int i = threadIdx.x; i < 4096; i += 256) {
      int r = i >> 6, c = i & 63;
      tile[r][c] = W[((size_t)h * 512 + d0 + r) * DH + t0 + c];
    }
    __syncthreads();
    for (int i = threadIdx.x; i < 4096; i += 256) {
      int t = i >> 6, d = i & 63;
      out[((size_t)(h * DH + t0 + t)) * 512 + d0 + d] = to_bf16(tile[d][t]);
    }
  }
}

// ---------------- 128xBN GEMM body, double-buffered counted-vmcnt staging ----------------
// MODE 0: C bf16 [M][N]; MODE 1: C f32 [M][N]; MODE 2: C bf16 TRANSPOSED (vT[col][row], ld 4096)
// NDMA per stage = 4 + NB -> counted wait must match (NB=1 -> vmcnt(5)).
template <int BN, int MODE, typename OutT>
__device__ __forceinline__ void gemm_body(const bf16* __restrict__ A, const bf16* __restrict__ Bt,
                                          OutT* __restrict__ C, int N, int K, int m0, int n0,
                                          bf16* sm) {
  constexpr int WN = BN / 2, JN = WN / 16, NB = BN / 32;
  int tid = threadIdx.x, lane = tid & 63, w = tid >> 6;
  int quad = lane >> 4, l16 = lane & 15;
  int wm = (w >> 1) * 64, wn = (w & 1) * WN;
  int srow = lane >> 3;            // row-within-8-group staged by this lane
  int sG = (lane & 7) ^ srow;      // source granule for stored position lane&7

  bf16* Asb[2] = { sm, sm + 8192 };
  bf16* Bsb[2] = { sm + 16384, sm + 16384 + BN * 64 };

  const bf16* ga[4];
  const bf16* gb[NB];
#pragma unroll
  for (int j = 0; j < 4; j++) ga[j] = A + (long)(m0 + (4 * j + w) * 8 + srow) * K + sG * 8;
#pragma unroll
  for (int j = 0; j < NB; j++) gb[j] = Bt + (long)(n0 + (4 * j + w) * 8 + srow) * K + sG * 8;

  auto stage = [&](int b) {
#pragma unroll
    for (int j = 0; j < 4; j++) { dma16(ga[j], &Asb[b][(4 * j + w) * 512]); ga[j] += 64; }
#pragma unroll
    for (int j = 0; j < NB; j++) { dma16(gb[j], &Bsb[b][(4 * j + w) * 512]); gb[j] += 64; }
  };

  f32x4 acc[4][JN] = {};
  stage(0);
  asm volatile("" ::: "memory");
  int cur = 0;
  const int NK = K >> 6;
  for (int s = 0; s < NK; ++s) {
    if (s + 1 < NK) {
      stage(cur ^ 1);
      if constexpr (NB == 4)      asm volatile("s_waitcnt vmcnt(8)" ::: "memory");
      else if constexpr (NB == 2) asm volatile("s_waitcnt vmcnt(6)" ::: "memory");
      else                        asm volatile("s_waitcnt vmcnt(5)" ::: "memory");
    } else {
      asm volatile("s_waitcnt vmcnt(0)" ::: "memory");
    }
    __builtin_amdgcn_s_barrier();      // tile s landed for all waves
    asm volatile("" ::: "memory");
    const bf16* Ac = Asb[cur];
    const bf16* Bc = Bsb[cur];
#pragma unroll
    for (int kk = 0; kk < 2; kk++) {
      bf16x8 af[4], bfr[JN];
#pragma unroll
      for (int i = 0; i < 4; i++) {
        int r = wm + i * 16 + l16;
        af[i] = *(const bf16x8*)&Ac[r * 64 + (((kk * 4 + quad) ^ r) & 7) * 8];
      }
#pragma unroll
      for (int j = 0; j < JN; j++) {
        int r = wn + j * 16 + l16;
        bfr[j] = *(const bf16x8*)&Bc[r * 64 + (((kk * 4 + quad) ^ r) & 7) * 8];
      }
#pragma unroll
      for (int i = 0; i < 4; i++)
#pragma unroll
        for (int j = 0; j < JN; j++)
          acc[i][j] = __builtin_amdgcn_mfma_f32_16x16x32_bf16(af[i], bfr[j], acc[i][j], 0, 0, 0);
    }
    asm volatile("" ::: "memory");
    __builtin_amdgcn_s_barrier();      // buf cur free for next stage's overwrite
    asm volatile("" ::: "memory");
    cur ^= 1;
  }

  if constexpr (MODE == 2) {
    bf16* tp = sm;  // [128][136] bf16 = 34.8 KB (sm is 64 KB)
#pragma unroll
    for (int i = 0; i < 4; i++)
#pragma unroll
      for (int j = 0; j < JN; j++)
#pragma unroll
        for (int r = 0; r < 4; r++)
          tp[(wn + j * 16 + l16) * 136 + wm + i * 16 + quad * 4 + r] = to_bf16(acc[i][j][r]);
    __syncthreads();
#pragma unroll
    for (int it = 0; it < 8; ++it) {
      int idx = it * 256 + tid;
      int rown = idx >> 4, c8 = (idx & 15) * 8;
      *(bf16x8*)&C[(size_t)(n0 + rown) * 4096 + m0 + c8] = *(const bf16x8*)&tp[rown * 136 + c8];
    }
  } else {
#pragma unroll
    for (int i = 0; i < 4; i++)
#pragma unroll
      for (int j = 0; j < JN; j++)
#pragma unroll
        for (int r = 0; r < 4; r++) {
          long row = m0 + wm + i * 16 + quad * 4 + r;
          long col = n0 + wn + j * 16 + l16;
          if constexpr (MODE == 0)
            C[row * N + col] = to_bf16(acc[i][j][r]);
          else
            C[row * N + col] = acc[i][j][r];
        }
  }
}

// merged q/k/v projections, exact 512-block grid; z==2 writes vT directly (transposed epilogue).
// R12: XCD-local m-grouping -- blocks on XCD g (=bid%8) own m-tiles g*4..g*4+3, so each
// XCD's L2 holds a 1 MB A-slice + the W panel instead of pulling from L3.
__global__ __launch_bounds__(256) void proj_gemm(const bf16* __restrict__ QKVb,
                                                 const bf16* __restrict__ Wt,
                                                 bf16* __restrict__ qkout,
                                                 bf16* __restrict__ vTout) {
  __shared__ __align__(16) bf16 sm[4 * 128 * 64];   // 64 KB
  int bid = blockIdx.x;
  if (bid < 256) {
    int z = bid >> 7;                 // 0:q 1:k
    int t = bid & 127;
    int g = t & 7, r = t >> 3;        // r 0..15
    int m0 = (g * 4 + (r & 3)) * 128; // mt 0..31 (XCD-grouped)
    int n0 = (r >> 2) * 128;          // nt 0..3
    gemm_body<128, 0, bf16>(QKVb + (size_t)z * 2097152, Wt + (size_t)z * 262144,
                            qkout + (size_t)z * 2097152, 512, 512, m0, n0, sm);
  } else {
    int t = bid - 256;                // 0..255 -> v projection, 4096x1024
    int g = t & 7, r = t >> 3;        // r 0..31
    int m0 = (g * 4 + (r & 3)) * 128; // mt 0..31 (XCD-grouped)
    int n0 = (r >> 2) * 128;          // nt 0..7
    gemm_body<128, 2, bf16>(QKVb + (size_t)2 * 2097152, Wt + (size_t)2 * 262144,
                            vTout, 1024, 512, m0, n0, sm);
  }
}

// output projection. R12: 128x32 tiles -> 512 blocks = 2 blocks/CU (8 waves/CU, was
// 1 block/CU = 1 wave/SIMD -- the R9-measured latency-exposed regime). 40 KB LDS.
// XCD-local m-grouping as in proj (x-slice 1 MB + Wob 1 MB fit each XCD L2).
__global__ __launch_bounds__(256) void out_gemm(const bf16* __restrict__ xin,
                                                const bf16* __restrict__ Wob,
                                                float* __restrict__ outp) {
  __shared__ __align__(16) bf16 sm[2 * 128 * 64 + 2 * 32 * 64];   // 40 KB
  int bid = blockIdx.x;               // 0..511
  int g = bid & 7, r = bid >> 3;      // r 0..63
  int m0 = (g * 4 + (r & 3)) * 128;   // mt 0..31 (XCD-grouped)
  int n0 = (r >> 2) * 32;             // nt 0..15
  gemm_body<32, 1, float>(xin, Wob, outp, 512, 1024, m0, n0, sm);
}

// ---------------- fused attention (R10 schedule, verified 109.6 us) ----------------
// qb,kb: [N][512]; vT: [1024][N]; x: [N][1024]
// Block = (head, dvh, q0): 64 q x 128 dv; 8 waves (cd,g); grid 512 = 2 blocks/CU (73.5 KB LDS).
// S runs ONE TILE AHEAD. Per iter: {load pf(t) -> regs; barrier; stage K(t+2),V(t+1);
// counted vmcnt; [S(t+1) MFMAs || PV(t) MFMAs] in one phase; exp(t+1)+pt-write; barrier}.
// 2 barriers/tile; __expf (NOT exp2f -- R11: libm path +7pt VALUBusy); no setprio (R11: hurt).
__global__ __launch_bounds__(512, 4) void attn(const bf16* __restrict__ qb,
                                               const bf16* __restrict__ kb,
                                               const bf16* __restrict__ vT,
                                               bf16* __restrict__ x) {
  __shared__ __align__(16) bf16 kt[2][64 * 128];   // [key][dk] swizzled, 2x16 KB
  __shared__ __align__(16) bf16 vt[2][128 * 64];   // [dv-half][key] swizzled, 2x16 KB
  __shared__ __align__(16) bf16 pt[64 * 72];       // [q][key], padded (9 KB)
  __shared__ float Lrow[64];

  const int bid = blockIdx.x;                      // 512 blocks
  const int xcd = bid & 7;
  const int head = xcd & 3;                        // one (head,dvh) pair per XCD
  const int dvh = xcd >> 2;                        // dv half 0..1
  const int q0 = (bid >> 3) * 64;                  // 0..4032
  const int tid = threadIdx.x;
  const int lane = tid & 63, w = tid >> 6;
  const int quad = lane >> 4, l16 = lane & 15;
  const int cd = w & 3;   // S: 16-key col tile; PV: 32-dv group
  const int g = w >> 2;   // q half

  // all-ones B-fragment: B[n][k] = (n==0) -> D[q][0] = sum_k P[q][k]
  bf16x8 onesf;
  {
    union { bf16 h[8]; bf16x8 v; } u;
    bf16 one = to_bf16(1.0f), zero = to_bf16(0.0f);
#pragma unroll
    for (int j = 0; j < 8; j++) u.h[j] = (l16 == 0) ? one : zero;
    onesf = u.v;
  }

  // preload q fragments (A-layout: m=l16, k=quad*8+j)
  bf16x8 qf[2][4];
#pragma unroll
  for (int i = 0; i < 2; i++) {
    const bf16* qrow = &qb[(size_t)(q0 + g * 32 + i * 16 + l16) * 512 + head * 128];
#pragma unroll
    for (int kk = 0; kk < 4; kk++) qf[i][kk] = *(const bf16x8*)&qrow[kk * 32 + quad * 8];
  }

  f32x4 oacc[2][2] = {};
  f32x4 oL[2] = {};
  const float scale = 1.0f / 64.0f;  // 1/sqrt(4096)

  // DMA source pointers (advance per staged tile). kt: 16 j-groups (4 key-rows x 128 dk);
  // vt: 16 j-groups (8 dv-rows x 64 keys). j = 2w+t2.
  const int j0 = 2 * w, j1 = 2 * w + 1;
  const bf16 *kp0, *kp1, *vp0, *vp1;
  {
    int r0 = 4 * j0 + (lane >> 4), r1 = 4 * j1 + (lane >> 4);
    int p = lane & 15;
    int G0 = (p & 8) | ((p ^ r0) & 7), G1 = (p & 8) | ((p ^ r1) & 7);
    kp0 = kb + (size_t)r0 * 512 + head * 128 + G0 * 8;
    kp1 = kb + (size_t)r1 * 512 + head * 128 + G1 * 8;
  }
  {
    int r0 = 8 * j0 + (lane >> 3), r1 = 8 * j1 + (lane >> 3);
    int p = lane & 7;
    int G0 = (p ^ r0) & 7, G1 = (p ^ r1) & 7;
    vp0 = vT + (size_t)(head * 256 + dvh * 128 + r0) * 4096 + G0 * 8;
    vp1 = vT + (size_t)(head * 256 + dvh * 128 + r1) * 4096 + G1 * 8;
  }

#define STAGE_K(b)                                      \
  do {                                                  \
    dma16(kp0, &kt[b][j0 * 512]);                       \
    dma16(kp1, &kt[b][j1 * 512]);                       \
    kp0 += 64 * 512; kp1 += 64 * 512;                   \
  } while (0)
#define STAGE_V(b)                                      \
  do {                                                  \
    dma16(vp0, &vt[b][j0 * 512]);                       \
    dma16(vp1, &vt[b][j1 * 512]);                       \
    vp0 += 64; vp1 += 64;                               \
  } while (0)

  // ---- prologue: stage K(0),V(0),K(1); compute S(0) -> pt ----
  STAGE_K(0);
  STAGE_V(0);
  STAGE_K(1);
  asm volatile("s_waitcnt vmcnt(2)" ::: "memory");   // K(0), V(0) landed; K(1) in flight
  __builtin_amdgcn_s_barrier();
  asm volatile("" ::: "memory");
  {
    const bf16* ktc = kt[0];
    f32x4 sacc[2] = {};
#pragma unroll
    for (int kk = 0; kk < 4; kk++) {
      int R = cd * 16 + l16;
      int G = kk * 4 + quad;
      bf16x8 kf = *(const bf16x8*)&ktc[R * 128 + (((G ^ R) & 7) | (G & 8)) * 8];
      sacc[0] = __builtin_amdgcn_mfma_f32_16x16x32_bf16(qf[0][kk], kf, sacc[0], 0, 0, 0);
      sacc[1] = __builtin_amdgcn_mfma_f32_16x16x32_bf16(qf[1][kk], kf, sacc[1], 0, 0, 0);
    }
#pragma unroll
    for (int i = 0; i < 2; i++)
#pragma unroll
      for (int r = 0; r < 4; r++)
        pt[(g * 32 + i * 16 + quad * 4 + r) * 72 + cd * 16 + l16] =
            to_bf16(__expf(sacc[i][r] * scale));
  }
  asm volatile("s_waitcnt lgkmcnt(0)" ::: "memory");
  __builtin_amdgcn_s_barrier();                      // pt(0) ready
  asm volatile("" ::: "memory");

  for (int t = 0; t < 64; ++t) {
    // ---- load pf(t) into registers, then free pt for S(t+1) ----
    bf16x8 pf[2][2];
#pragma unroll
    for (int kk = 0; kk < 2; kk++)
#pragma unroll
      for (int i = 0; i < 2; i++)
        pf[kk][i] = *(const bf16x8*)&pt[(g * 32 + i * 16 + l16) * 72 + kk * 32 + quad * 8];
    asm volatile("s_waitcnt lgkmcnt(0)" ::: "memory");
    __builtin_amdgcn_s_barrier();        // all waves hold pf(t); pt free
    asm volatile("" ::: "memory");

    // ---- stage ahead: K(t+2) into buf t%2, V(t+1) into buf (t+1)%2 ----
    if (t < 62) STAGE_K(t & 1);
    if (t < 63) STAGE_V((t + 1) & 1);
    if (t < 62)      asm volatile("s_waitcnt vmcnt(4)" ::: "memory");  // K(t+1),V(t) landed
    else if (t == 62) asm volatile("s_waitcnt vmcnt(2)" ::: "memory");
    else              asm volatile("s_waitcnt vmcnt(0)" ::: "memory");

    // ---- merged phase: S(t+1) || PV(t) ----
    if (t < 63) {
      const bf16* ktc = kt[(t + 1) & 1];
      const bf16* vtc = vt[t & 1];
      f32x4 sacc[2] = {};
#pragma unroll
      for (int kk = 0; kk < 4; kk++) {
        int R = cd * 16 + l16;
        int G = kk * 4 + quad;
        bf16x8 kf = *(const bf16x8*)&ktc[R * 128 + (((G ^ R) & 7) | (G & 8)) * 8];
        sacc[0] = __builtin_amdgcn_mfma_f32_16x16x32_bf16(qf[0][kk], kf, sacc[0], 0, 0, 0);
        sacc[1] = __builtin_amdgcn_mfma_f32_16x16x32_bf16(qf[1][kk], kf, sacc[1], 0, 0, 0);
      }
#pragma unroll
      for (int kk = 0; kk < 2; kk++) {
#pragma unroll
        for (int c = 0; c < 2; c++) {
          int R = cd * 32 + c * 16 + l16;
          int G = kk * 4 + quad;
          bf16x8 vf = *(const bf16x8*)&vtc[R * 64 + ((G ^ R) & 7) * 8];
#pragma unroll
          for (int i = 0; i < 2; i++)
            oacc[i][c] = __builtin_amdgcn_mfma_f32_16x16x32_bf16(pf[kk][i], vf, oacc[i][c], 0, 0, 0);
        }
        if (cd == 3) {
#pragma unroll
          for (int i = 0; i < 2; i++)
            oL[i] = __builtin_amdgcn_mfma_f32_16x16x32_bf16(pf[kk][i], onesf, oL[i], 0, 0, 0);
        }
      }
      // exp(t+1) + pt write (trails the S MFMAs)
#pragma unroll
      for (int i = 0; i < 2; i++)
#pragma unroll
        for (int r = 0; r < 4; r++)
          pt[(g * 32 + i * 16 + quad * 4 + r) * 72 + cd * 16 + l16] =
              to_bf16(__expf(sacc[i][r] * scale));
    } else {
      // last iter: PV(63) only
      const bf16* vtc = vt[t & 1];
#pragma unroll
      for (int kk = 0; kk < 2; kk++) {
#pragma unroll
        for (int c = 0; c < 2; c++) {
          int R = cd * 32 + c * 16 + l16;
          int G = kk * 4 + quad;
          bf16x8 vf = *(const bf16x8*)&vtc[R * 64 + ((G ^ R) & 7) * 8];
#pragma unroll
          for (int i = 0; i < 2; i++)
            oacc[i][c] = __builtin_amdgcn_mfma_f32_16x16x32_bf16(pf[kk][i], vf, oacc[i][c], 0, 0, 0);
        }
        if (cd == 3) {
#pragma unroll
          for (int i = 0; i < 2; i++)
            oL[i] = __builtin_amdgcn_mfma_f32_16x16x32_bf16(pf[kk][i], onesf, oL[i], 0, 0, 0);
        }
      }
    }
    asm volatile("s_waitcnt lgkmcnt(0)" ::: "memory");   // pt(t+1) writes visible
    __builtin_amdgcn_s_barrier();        // pt(t+1) ready; buffers rotate
    asm volatile("" ::: "memory");
  }
#undef STAGE_K
#undef STAGE_V

  // L at lanes l16==0 of cd==3 waves (C-layout col 0)
  if (cd == 3 && l16 == 0) {
#pragma unroll
    for (int i = 0; i < 2; i++)
#pragma unroll
      for (int r = 0; r < 4; r++) Lrow[g * 32 + i * 16 + quad * 4 + r] = oL[i][r];
  }
  __syncthreads();

  // normalize + write x[n][head*256 + dvh*128 + dv]
#pragma unroll
  for (int i = 0; i < 2; i++)
#pragma unroll
    for (int c = 0; c < 2; c++)
#pragma unroll
      for (int r = 0; r < 4; r++) {
        int row = g * 32 + i * 16 + quad * 4 + r;
        float v = oacc[i][c][r] / Lrow[row];
        x[(size_t)(q0 + row) * 1024 + head * 256 + dvh * 128 + cd * 32 + c * 16 + l16] =
            to_bf16(v);
      }
}

// ---------------- launch ----------------
extern "C" void kernel_launch(void* const* d_in, const int* in_sizes, int n_in,
                              void* d_out, int out_size, void* d_ws, size_t ws_size,
                              hipStream_t stream) {
  const float* Q  = (const float*)d_in[0];
  const float* Km = (const float*)d_in[1];
  const float* V  = (const float*)d_in[2];
  const float* Wq = (const float*)d_in[3];
  const float* Wk = (const float*)d_in[4];
  const float* Wv = (const float*)d_in[5];
  const float* Wo = (const float*)d_in[6];
  float* out = (float*)d_out;

  bf16* ws  = (bf16*)d_ws;
  bf16* Qb  = ws;                 // 4096x512   (Qb,Kb,Vb contiguous)
  bf16* Kb  = Qb + 2097152;
  bf16* Vb  = Kb + 2097152;
  bf16* Wqt = Vb + 2097152;       // 512x512  (Wqt,Wkt,Wvt contiguous)
  bf16* Wkt = Wqt + 262144;
  bf16* Wvt = Wkt + 262144;       // 1024x512 (Bt)
  bf16* Wob = Wvt + 524288;       // 512x1024 (Bt = Wo as-is)
  bf16* qb  = Wob + 524288;       // 4096x512   (qb,kb contiguous)
  bf16* kb  = qb + 2097152;
  bf16* vT  = kb + 2097152;       // 1024x4096  (written directly by proj z==2)
  bf16* x   = vT + 4194304;       // 4096x1024

  prep<<<3712, 256, 0, stream>>>(Q, Km, V, Wo, Qb, Kb, Vb, Wob, Wq, Wk, Wv, Wqt, Wkt, Wvt);

  proj_gemm<<<512, 256, 0, stream>>>(Qb, Wqt, qb, vT);

  attn<<<512, 512, 0, stream>>>(qb, kb, vT, x);

  out_gemm<<<512, 256, 0, stream>>>(x, Wob, out);
}

// Round 13
// 216.060 us; speedup vs baseline: 1.0559x; 1.0051x over previous
//
#include <hip/hip_runtime.h>
#include <hip/hip_bf16.h>
#include <type_traits>

typedef __hip_bfloat16 bf16;
typedef __attribute__((ext_vector_type(8))) short bf16x8;
typedef __attribute__((ext_vector_type(4))) float f32x4;

#define N_LOC 4096

__device__ __forceinline__ bf16 to_bf16(float f) { return __float2bfloat16(f); }

// async global->LDS DMA, 16B per lane; LDS dest = wave-uniform base + lane*16
__device__ __forceinline__ void dma16(const bf16* g, bf16* l) {
  __builtin_amdgcn_global_load_lds((const __attribute__((address_space(1))) unsigned int*)g,
                                   (__attribute__((address_space(3))) unsigned int*)l, 16, 0, 0);
}

// ---------------- prep: W transpose-pack ONLY (R13: Q/K/V/Wo converts fused into GEMMs) ----------
__global__ __launch_bounds__(256) void prep(const float* __restrict__ Wq, const float* __restrict__ Wk,
                                            const float* __restrict__ Wv,
                                            bf16* __restrict__ oq, bf16* __restrict__ ok,
                                            bf16* __restrict__ ov) {
  __shared__ float tile[64][65];
  int pid = blockIdx.x;                   // 0..383  (x 8, y 16, z 3)
  int z = pid >> 7;
  int rem = pid & 127;
  int xx = rem & 7, y = rem >> 3;
  const float* W = (z == 0) ? Wq : (z == 1) ? Wk : Wv;
  bf16* out = (z == 0) ? oq : (z == 1) ? ok : ov;
  int DH = (z == 2) ? 256 : 128;
  int nt = DH >> 6;
  if (y >= 4 * nt) return;
  int h = y / nt, tt = y - h * nt;
  int d0 = xx * 64, t0 = tt * 64;
  for (int i = threadIdx.x; i < 4096; i += 256) {
    int r = i >> 6, c = i & 63;
    tile[r][c] = W[((size_t)h * 512 + d0 + r) * DH + t0 + c];
  }
  __syncthreads();
  for (int i = threadIdx.x; i < 4096; i += 256) {
    int t = i >> 6, d = i & 63;
    out[((size_t)(h * DH + t0 + t)) * 512 + d0 + d] = to_bf16(tile[d][t]);
  }
}

// ---------------- 128xBN GEMM body, double-buffered counted-vmcnt staging ----------------
// MODE 0: C bf16 [M][N]; MODE 1: C f32 [M][N]; MODE 2: C bf16 TRANSPOSED (vT[col][row], ld 4096)
// F32A/F32B: operand is f32 in global; staged via float4-load + RNE pack + ds_write_b128
// into the SAME XOR-swizzled layout dma16 produces (dest = wave base + lane*16B).
// Counted vmcnt counts only remaining dma16s; lgkmcnt(0) before barrier covers ds_writes.
template <int BN, int MODE, bool F32A, bool F32B, typename OutT>
__device__ __forceinline__ void gemm_body(const void* __restrict__ Av, const void* __restrict__ Btv,
                                          OutT* __restrict__ C, int N, int K, int m0, int n0,
                                          bf16* sm) {
  constexpr int WN = BN / 2, JN = WN / 16, NB = BN / 32;
  constexpr int NDMA = (F32A ? 0 : 4) + (F32B ? 0 : NB);
  int tid = threadIdx.x, lane = tid & 63, w = tid >> 6;
  int quad = lane >> 4, l16 = lane & 15;
  int wm = (w >> 1) * 64, wn = (w & 1) * WN;
  int srow = lane >> 3;            // row-within-8-group staged by this lane
  int sG = (lane & 7) ^ srow;      // source granule for stored position lane&7

  bf16* Asb[2] = { sm, sm + 8192 };
  bf16* Bsb[2] = { sm + 16384, sm + 16384 + BN * 64 };

  const bf16* Ab = (const bf16*)Av;
  const float* Af = (const float*)Av;
  const bf16* Bb = (const bf16*)Btv;
  const float* Bf = (const float*)Btv;

  long aoff[4];
  long boff[NB];
#pragma unroll
  for (int j = 0; j < 4; j++) aoff[j] = (long)(m0 + (4 * j + w) * 8 + srow) * K + sG * 8;
#pragma unroll
  for (int j = 0; j < NB; j++) boff[j] = (long)(n0 + (4 * j + w) * 8 + srow) * K + sG * 8;

  auto stage = [&](int b) {
#pragma unroll
    for (int j = 0; j < 4; j++) {
      if constexpr (F32A) {
        float4 xa = *(const float4*)&Af[aoff[j]];
        float4 xb = *(const float4*)&Af[aoff[j] + 4];
        union { bf16 h[8]; bf16x8 v; } u;
        u.h[0] = to_bf16(xa.x); u.h[1] = to_bf16(xa.y); u.h[2] = to_bf16(xa.z); u.h[3] = to_bf16(xa.w);
        u.h[4] = to_bf16(xb.x); u.h[5] = to_bf16(xb.y); u.h[6] = to_bf16(xb.z); u.h[7] = to_bf16(xb.w);
        *(bf16x8*)&Asb[b][(4 * j + w) * 512 + lane * 8] = u.v;
      } else {
        dma16(&Ab[aoff[j]], &Asb[b][(4 * j + w) * 512]);
      }
      aoff[j] += 64;
    }
#pragma unroll
    for (int j = 0; j < NB; j++) {
      if constexpr (F32B) {
        float4 xa = *(const float4*)&Bf[boff[j]];
        float4 xb = *(const float4*)&Bf[boff[j] + 4];
        union { bf16 h[8]; bf16x8 v; } u;
        u.h[0] = to_bf16(xa.x); u.h[1] = to_bf16(xa.y); u.h[2] = to_bf16(xa.z); u.h[3] = to_bf16(xa.w);
        u.h[4] = to_bf16(xb.x); u.h[5] = to_bf16(xb.y); u.h[6] = to_bf16(xb.z); u.h[7] = to_bf16(xb.w);
        *(bf16x8*)&Bsb[b][(4 * j + w) * 512 + lane * 8] = u.v;
      } else {
        dma16(&Bb[boff[j]], &Bsb[b][(4 * j + w) * 512]);
      }
      boff[j] += 64;
    }
  };

  f32x4 acc[4][JN] = {};
  stage(0);
  asm volatile("" ::: "memory");
  int cur = 0;
  const int NK = K >> 6;
  for (int s = 0; s < NK; ++s) {
    if (s + 1 < NK) {
      stage(cur ^ 1);
      if constexpr (NDMA == 8)      asm volatile("s_waitcnt vmcnt(8)" ::: "memory");
      else if constexpr (NDMA == 6) asm volatile("s_waitcnt vmcnt(6)" ::: "memory");
      else if constexpr (NDMA == 5) asm volatile("s_waitcnt vmcnt(5)" ::: "memory");
      else if constexpr (NDMA == 4) asm volatile("s_waitcnt vmcnt(4)" ::: "memory");
      else if constexpr (NDMA == 2) asm volatile("s_waitcnt vmcnt(2)" ::: "memory");
      else                          asm volatile("s_waitcnt vmcnt(0)" ::: "memory");
    } else {
      asm volatile("s_waitcnt vmcnt(0)" ::: "memory");
    }
    asm volatile("s_waitcnt lgkmcnt(0)" ::: "memory");   // F32-side ds_writes visible
    __builtin_amdgcn_s_barrier();      // tile s landed for all waves
    asm volatile("" ::: "memory");
    const bf16* Ac = Asb[cur];
    const bf16* Bc = Bsb[cur];
#pragma unroll
    for (int kk = 0; kk < 2; kk++) {
      bf16x8 af[4], bfr[JN];
#pragma unroll
      for (int i = 0; i < 4; i++) {
        int r = wm + i * 16 + l16;
        af[i] = *(const bf16x8*)&Ac[r * 64 + (((kk * 4 + quad) ^ r) & 7) * 8];
      }
#pragma unroll
      for (int j = 0; j < JN; j++) {
        int r = wn + j * 16 + l16;
        bfr[j] = *(const bf16x8*)&Bc[r * 64 + (((kk * 4 + quad) ^ r) & 7) * 8];
      }
#pragma unroll
      for (int i = 0; i < 4; i++)
#pragma unroll
        for (int j = 0; j < JN; j++)
          acc[i][j] = __builtin_amdgcn_mfma_f32_16x16x32_bf16(af[i], bfr[j], acc[i][j], 0, 0, 0);
    }
    asm volatile("" ::: "memory");
    __builtin_amdgcn_s_barrier();      // buf cur free for next stage's overwrite
    asm volatile("" ::: "memory");
    cur ^= 1;
  }

  if constexpr (MODE == 2) {
    bf16* tp = sm;  // [128][136] bf16 = 34.8 KB (sm is 64 KB)
#pragma unroll
    for (int i = 0; i < 4; i++)
#pragma unroll
      for (int j = 0; j < JN; j++)
#pragma unroll
        for (int r = 0; r < 4; r++)
          tp[(wn + j * 16 + l16) * 136 + wm + i * 16 + quad * 4 + r] = to_bf16(acc[i][j][r]);
    __syncthreads();
#pragma unroll
    for (int it = 0; it < 8; ++it) {
      int idx = it * 256 + tid;
      int rown = idx >> 4, c8 = (idx & 15) * 8;
      *(bf16x8*)&C[(size_t)(n0 + rown) * 4096 + m0 + c8] = *(const bf16x8*)&tp[rown * 136 + c8];
    }
  } else {
#pragma unroll
    for (int i = 0; i < 4; i++)
#pragma unroll
      for (int j = 0; j < JN; j++)
#pragma unroll
        for (int r = 0; r < 4; r++) {
          long row = m0 + wm + i * 16 + quad * 4 + r;
          long col = n0 + wn + j * 16 + l16;
          if constexpr (MODE == 0)
            C[row * N + col] = to_bf16(acc[i][j][r]);
          else
            C[row * N + col] = acc[i][j][r];
        }
  }
}

// merged q/k/v projections reading f32 Q/K/V directly (conversion fused into staging);
// exact 512-block grid; z==2 writes vT directly (transposed epilogue). R10 tile mapping.
__global__ __launch_bounds__(256) void proj_gemm(const float* __restrict__ Q,
                                                 const float* __restrict__ Kin,
                                                 const float* __restrict__ V,
                                                 const bf16* __restrict__ Wt,
                                                 bf16* __restrict__ qkout,
                                                 bf16* __restrict__ vTout) {
  __shared__ __align__(16) bf16 sm[4 * 128 * 64];   // 64 KB
  int bid = blockIdx.x;
  if (bid < 256) {
    int z = bid >> 7;                 // 0:q 1:k
    int t = bid & 127;
    int m0 = (t & 31) * 128, n0 = (t >> 5) * 128;
    const float* A = (z == 0) ? Q : Kin;
    gemm_body<128, 0, true, false, bf16>(A, Wt + (size_t)z * 262144,
                                         qkout + (size_t)z * 2097152, 512, 512, m0, n0, sm);
  } else {
    int t = bid - 256;                // 0..255 -> v projection, 4096x1024
    int m0 = (t & 31) * 128, n0 = (t >> 5) * 128;
    gemm_body<128, 2, true, false, bf16>(V, Wt + (size_t)2 * 262144,
                                         vTout, 1024, 512, m0, n0, sm);
  }
}

// output projection: 128x64 tiles -> 256 blocks (R10 config); Wo read as f32 directly.
__global__ __launch_bounds__(256) void out_gemm(const bf16* __restrict__ xin,
                                                const float* __restrict__ Wo,
                                                float* __restrict__ outp) {
  __shared__ __align__(16) bf16 sm[2 * 128 * 64 + 2 * 64 * 64];   // 48 KB
  gemm_body<64, 1, false, true, float>(xin, Wo, outp, 512, 1024,
                                       blockIdx.x * 128, blockIdx.y * 64, sm);
}

// ---------------- fused attention (R10 schedule, verified best: 109.6 us) ----------------
// qb,kb: [N][512]; vT: [1024][N]; x: [N][1024]
// Block = (head, dvh, q0): 64 q x 128 dv; 8 waves (cd,g); grid 512 = 2 blocks/CU (73.5 KB LDS).
// S runs ONE TILE AHEAD. Per iter: {load pf(t) -> regs; barrier; stage K(t+2),V(t+1);
// counted vmcnt; [S(t+1) MFMAs || PV(t) MFMAs] in one phase; exp(t+1)+pt-write; barrier}.
// 2 barriers/tile; __expf (NOT exp2f -- R11); no setprio (R11).
__global__ __launch_bounds__(512, 4) void attn(const bf16* __restrict__ qb,
                                               const bf16* __restrict__ kb,
                                               const bf16* __restrict__ vT,
                                               bf16* __restrict__ x) {
  __shared__ __align__(16) bf16 kt[2][64 * 128];   // [key][dk] swizzled, 2x16 KB
  __shared__ __align__(16) bf16 vt[2][128 * 64];   // [dv-half][key] swizzled, 2x16 KB
  __shared__ __align__(16) bf16 pt[64 * 72];       // [q][key], padded (9 KB)
  __shared__ float Lrow[64];

  const int bid = blockIdx.x;                      // 512 blocks
  const int xcd = bid & 7;
  const int head = xcd & 3;                        // one (head,dvh) pair per XCD
  const int dvh = xcd >> 2;                        // dv half 0..1
  const int q0 = (bid >> 3) * 64;                  // 0..4032
  const int tid = threadIdx.x;
  const int lane = tid & 63, w = tid >> 6;
  const int quad = lane >> 4, l16 = lane & 15;
  const int cd = w & 3;   // S: 16-key col tile; PV: 32-dv group
  const int g = w >> 2;   // q half

  // all-ones B-fragment: B[n][k] = (n==0) -> D[q][0] = sum_k P[q][k]
  bf16x8 onesf;
  {
    union { bf16 h[8]; bf16x8 v; } u;
    bf16 one = to_bf16(1.0f), zero = to_bf16(0.0f);
#pragma unroll
    for (int j = 0; j < 8; j++) u.h[j] = (l16 == 0) ? one : zero;
    onesf = u.v;
  }

  // preload q fragments (A-layout: m=l16, k=quad*8+j)
  bf16x8 qf[2][4];
#pragma unroll
  for (int i = 0; i < 2; i++) {
    const bf16* qrow = &qb[(size_t)(q0 + g * 32 + i * 16 + l16) * 512 + head * 128];
#pragma unroll
    for (int kk = 0; kk < 4; kk++) qf[i][kk] = *(const bf16x8*)&qrow[kk * 32 + quad * 8];
  }

  f32x4 oacc[2][2] = {};
  f32x4 oL[2] = {};
  const float scale = 1.0f / 64.0f;  // 1/sqrt(4096)

  // DMA source pointers (advance per staged tile). kt: 16 j-groups (4 key-rows x 128 dk);
  // vt: 16 j-groups (8 dv-rows x 64 keys). j = 2w+t2.
  const int j0 = 2 * w, j1 = 2 * w + 1;
  const bf16 *kp0, *kp1, *vp0, *vp1;
  {
    int r0 = 4 * j0 + (lane >> 4), r1 = 4 * j1 + (lane >> 4);
    int p = lane & 15;
    int G0 = (p & 8) | ((p ^ r0) & 7), G1 = (p & 8) | ((p ^ r1) & 7);
    kp0 = kb + (size_t)r0 * 512 + head * 128 + G0 * 8;
    kp1 = kb + (size_t)r1 * 512 + head * 128 + G1 * 8;
  }
  {
    int r0 = 8 * j0 + (lane >> 3), r1 = 8 * j1 + (lane >> 3);
    int p = lane & 7;
    int G0 = (p ^ r0) & 7, G1 = (p ^ r1) & 7;
    vp0 = vT + (size_t)(head * 256 + dvh * 128 + r0) * 4096 + G0 * 8;
    vp1 = vT + (size_t)(head * 256 + dvh * 128 + r1) * 4096 + G1 * 8;
  }

#define STAGE_K(b)                                      \
  do {                                                  \
    dma16(kp0, &kt[b][j0 * 512]);                       \
    dma16(kp1, &kt[b][j1 * 512]);                       \
    kp0 += 64 * 512; kp1 += 64 * 512;                   \
  } while (0)
#define STAGE_V(b)                                      \
  do {                                                  \
    dma16(vp0, &vt[b][j0 * 512]);                       \
    dma16(vp1, &vt[b][j1 * 512]);                       \
    vp0 += 64; vp1 += 64;                               \
  } while (0)

  // ---- prologue: stage K(0),V(0),K(1); compute S(0) -> pt ----
  STAGE_K(0);
  STAGE_V(0);
  STAGE_K(1);
  asm volatile("s_waitcnt vmcnt(2)" ::: "memory");   // K(0), V(0) landed; K(1) in flight
  __builtin_amdgcn_s_barrier();
  asm volatile("" ::: "memory");
  {
    const bf16* ktc = kt[0];
    f32x4 sacc[2] = {};
#pragma unroll
    for (int kk = 0; kk < 4; kk++) {
      int R = cd * 16 + l16;
      int G = kk * 4 + quad;
      bf16x8 kf = *(const bf16x8*)&ktc[R * 128 + (((G ^ R) & 7) | (G & 8)) * 8];
      sacc[0] = __builtin_amdgcn_mfma_f32_16x16x32_bf16(qf[0][kk], kf, sacc[0], 0, 0, 0);
      sacc[1] = __builtin_amdgcn_mfma_f32_16x16x32_bf16(qf[1][kk], kf, sacc[1], 0, 0, 0);
    }
#pragma unroll
    for (int i = 0; i < 2; i++)
#pragma unroll
      for (int r = 0; r < 4; r++)
        pt[(g * 32 + i * 16 + quad * 4 + r) * 72 + cd * 16 + l16] =
            to_bf16(__expf(sacc[i][r] * scale));
  }
  asm volatile("s_waitcnt lgkmcnt(0)" ::: "memory");
  __builtin_amdgcn_s_barrier();                      // pt(0) ready
  asm volatile("" ::: "memory");

  for (int t = 0; t < 64; ++t) {
    // ---- load pf(t) into registers, then free pt for S(t+1) ----
    bf16x8 pf[2][2];
#pragma unroll
    for (int kk = 0; kk < 2; kk++)
#pragma unroll
      for (int i = 0; i < 2; i++)
        pf[kk][i] = *(const bf16x8*)&pt[(g * 32 + i * 16 + l16) * 72 + kk * 32 + quad * 8];
    asm volatile("s_waitcnt lgkmcnt(0)" ::: "memory");
    __builtin_amdgcn_s_barrier();        // all waves hold pf(t); pt free
    asm volatile("" ::: "memory");

    // ---- stage ahead: K(t+2) into buf t%2, V(t+1) into buf (t+1)%2 ----
    if (t < 62) STAGE_K(t & 1);
    if (t < 63) STAGE_V((t + 1) & 1);
    if (t < 62)      asm volatile("s_waitcnt vmcnt(4)" ::: "memory");  // K(t+1),V(t) landed
    else if (t == 62) asm volatile("s_waitcnt vmcnt(2)" ::: "memory");
    else              asm volatile("s_waitcnt vmcnt(0)" ::: "memory");

    // ---- merged phase: S(t+1) || PV(t) ----
    if (t < 63) {
      const bf16* ktc = kt[(t + 1) & 1];
      const bf16* vtc = vt[t & 1];
      f32x4 sacc[2] = {};
#pragma unroll
      for (int kk = 0; kk < 4; kk++) {
        int R = cd * 16 + l16;
        int G = kk * 4 + quad;
        bf16x8 kf = *(const bf16x8*)&ktc[R * 128 + (((G ^ R) & 7) | (G & 8)) * 8];
        sacc[0] = __builtin_amdgcn_mfma_f32_16x16x32_bf16(qf[0][kk], kf, sacc[0], 0, 0, 0);
        sacc[1] = __builtin_amdgcn_mfma_f32_16x16x32_bf16(qf[1][kk], kf, sacc[1], 0, 0, 0);
      }
#pragma unroll
      for (int kk = 0; kk < 2; kk++) {
#pragma unroll
        for (int c = 0; c < 2; c++) {
          int R = cd * 32 + c * 16 + l16;
          int G = kk * 4 + quad;
          bf16x8 vf = *(const bf16x8*)&vtc[R * 64 + ((G ^ R) & 7) * 8];
#pragma unroll
          for (int i = 0; i < 2; i++)
            oacc[i][c] = __builtin_amdgcn_mfma_f32_16x16x32_bf16(pf[kk][i], vf, oacc[i][c], 0, 0, 0);
        }
        if (cd == 3) {
#pragma unroll
          for (int i = 0; i < 2; i++)
            oL[i] = __builtin_amdgcn_mfma_f32_16x16x32_bf16(pf[kk][i], onesf, oL[i], 0, 0, 0);
        }
      }
      // exp(t+1) + pt write (trails the S MFMAs)
#pragma unroll
      for (int i = 0; i < 2; i++)
#pragma unroll
        for (int r = 0; r < 4; r++)
          pt[(g * 32 + i * 16 + quad * 4 + r) * 72 + cd * 16 + l16] =
              to_bf16(__expf(sacc[i][r] * scale));
    } else {
      // last iter: PV(63) only
      const bf16* vtc = vt[t & 1];
#pragma unroll
      for (int kk = 0; kk < 2; kk++) {
#pragma unroll
        for (int c = 0; c < 2; c++) {
          int R = cd * 32 + c * 16 + l16;
          int G = kk * 4 + quad;
          bf16x8 vf = *(const bf16x8*)&vtc[R * 64 + ((G ^ R) & 7) * 8];
#pragma unroll
          for (int i = 0; i < 2; i++)
            oacc[i][c] = __builtin_amdgcn_mfma_f32_16x16x32_bf16(pf[kk][i], vf, oacc[i][c], 0, 0, 0);
        }
        if (cd == 3) {
#pragma unroll
          for (int i = 0; i < 2; i++)
            oL[i] = __builtin_amdgcn_mfma_f32_16x16x32_bf16(pf[kk][i], onesf, oL[i], 0, 0, 0);
        }
      }
    }
    asm volatile("s_waitcnt lgkmcnt(0)" ::: "memory");   // pt(t+1) writes visible
    __builtin_amdgcn_s_barrier();        // pt(t+1) ready; buffers rotate
    asm volatile("" ::: "memory");
  }
#undef STAGE_K
#undef STAGE_V

  // L at lanes l16==0 of cd==3 waves (C-layout col 0)
  if (cd == 3 && l16 == 0) {
#pragma unroll
    for (int i = 0; i < 2; i++)
#pragma unroll
      for (int r = 0; r < 4; r++) Lrow[g * 32 + i * 16 + quad * 4 + r] = oL[i][r];
  }
  __syncthreads();

  // normalize + write x[n][head*256 + dvh*128 + dv]
#pragma unroll
  for (int i = 0; i < 2; i++)
#pragma unroll
    for (int c = 0; c < 2; c++)
#pragma unroll
      for (int r = 0; r < 4; r++) {
        int row = g * 32 + i * 16 + quad * 4 + r;
        float v = oacc[i][c][r] / Lrow[row];
        x[(size_t)(q0 + row) * 1024 + head * 256 + dvh * 128 + cd * 32 + c * 16 + l16] =
            to_bf16(v);
      }
}

// ---------------- launch ----------------
extern "C" void kernel_launch(void* const* d_in, const int* in_sizes, int n_in,
                              void* d_out, int out_size, void* d_ws, size_t ws_size,
                              hipStream_t stream) {
  const float* Q  = (const float*)d_in[0];
  const float* Km = (const float*)d_in[1];
  const float* V  = (const float*)d_in[2];
  const float* Wq = (const float*)d_in[3];
  const float* Wk = (const float*)d_in[4];
  const float* Wv = (const float*)d_in[5];
  const float* Wo = (const float*)d_in[6];
  float* out = (float*)d_out;

  bf16* ws  = (bf16*)d_ws;
  bf16* Wqt = ws;                 // 512x512  (Wqt,Wkt,Wvt contiguous)
  bf16* Wkt = Wqt + 262144;
  bf16* Wvt = Wkt + 262144;       // 1024x512 (Bt)
  bf16* qb  = Wvt + 524288;       // 4096x512   (qb,kb contiguous)
  bf16* kb  = qb + 2097152;
  bf16* vT  = kb + 2097152;       // 1024x4096  (written directly by proj z==2)
  bf16* x   = vT + 4194304;       // 4096x1024

  prep<<<384, 256, 0, stream>>>(Wq, Wk, Wv, Wqt, Wkt, Wvt);

  proj_gemm<<<512, 256, 0, stream>>>(Q, Km, V, Wqt, qb, vT);

  attn<<<512, 512, 0, stream>>>(qb, kb, vT, x);

  out_gemm<<<dim3(32, 8), 256, 0, stream>>>(x, Wo, out);
}

// Round 14
// 212.842 us; speedup vs baseline: 1.0718x; 1.0151x over previous
//
#include <hip/hip_runtime.h>
#include <hip/hip_bf16.h>
#include <type_traits>

typedef __hip_bfloat16 bf16;
typedef __attribute__((ext_vector_type(8))) short bf16x8;
typedef __attribute__((ext_vector_type(4))) float f32x4;

#define N_LOC 4096

__device__ __forceinline__ bf16 to_bf16(float f) { return __float2bfloat16(f); }

// async global->LDS DMA, 16B per lane; LDS dest = wave-uniform base + lane*16
__device__ __forceinline__ void dma16(const bf16* g, bf16* l) {
  __builtin_amdgcn_global_load_lds((const __attribute__((address_space(1))) unsigned int*)g,
                                   (__attribute__((address_space(3))) unsigned int*)l, 16, 0, 0);
}

// ---------------- prep: fused {f32->bf16 convert of Q,K,V,Wo} + {W transpose-pack} ----------------
__global__ __launch_bounds__(256) void prep(const float* __restrict__ Q, const float* __restrict__ K,
                                            const float* __restrict__ V, const float* __restrict__ Wo,
                                            bf16* __restrict__ Qb, bf16* __restrict__ Kb,
                                            bf16* __restrict__ Vb, bf16* __restrict__ Wob,
                                            const float* __restrict__ Wq, const float* __restrict__ Wk,
                                            const float* __restrict__ Wv,
                                            bf16* __restrict__ oq, bf16* __restrict__ ok,
                                            bf16* __restrict__ ov) {
  __shared__ float tile[64][65];
  if (blockIdx.x < 3328) {
    long i = ((long)blockIdx.x * 256 + threadIdx.x) * 8;
    const float* src;
    bf16* dst;
    long off;
    if (i < 2097152)      { src = Q;  dst = Qb;  off = i; }
    else if (i < 4194304) { src = K;  dst = Kb;  off = i - 2097152; }
    else if (i < 6291456) { src = V;  dst = Vb;  off = i - 4194304; }
    else                  { src = Wo; dst = Wob; off = i - 6291456; }
    float4 a = *(const float4*)&src[off];
    float4 b = *(const float4*)&src[off + 4];
    union { bf16 h[8]; bf16x8 v; } u;
    u.h[0] = to_bf16(a.x); u.h[1] = to_bf16(a.y); u.h[2] = to_bf16(a.z); u.h[3] = to_bf16(a.w);
    u.h[4] = to_bf16(b.x); u.h[5] = to_bf16(b.y); u.h[6] = to_bf16(b.z); u.h[7] = to_bf16(b.w);
    *(bf16x8*)&dst[off] = u.v;
  } else {
    int pid = blockIdx.x - 3328;            // 0..383  (old dims: x 8, y 16, z 3)
    int z = pid >> 7;
    int rem = pid & 127;
    int xx = rem & 7, y = rem >> 3;
    const float* W = (z == 0) ? Wq : (z == 1) ? Wk : Wv;
    bf16* out = (z == 0) ? oq : (z == 1) ? ok : ov;
    int DH = (z == 2) ? 256 : 128;
    int nt = DH >> 6;
    if (y >= 4 * nt) return;
    int h = y / nt, tt = y - h * nt;
    int d0 = xx * 64, t0 = tt * 64;
    for (int i = threadIdx.x; i < 4096; i += 256) {
      int r = i >> 6, c = i & 63;
      tile[r][c] = W[((size_t)h * 512 + d0 + r) * DH + t0 + c];
    }
    __syncthreads();
    for (int i = threadIdx.x; i < 4096; i += 256) {
      int t = i >> 6, d = i & 63;
      out[((size_t)(h * DH + t0 + t)) * 512 + d0 + d] = to_bf16(tile[d][t]);
    }
  }
}

// ---------------- 128xBN GEMM body, double-buffered counted-vmcnt staging ----------------
// MODE 0: C bf16 [M][N]; MODE 1: C f32 [M][N]; MODE 2: C bf16 TRANSPOSED (vT[col][row], ld 4096)
template <int BN, int MODE, typename OutT>
__device__ __forceinline__ void gemm_body(const bf16* __restrict__ A, const bf16* __restrict__ Bt,
                                          OutT* __restrict__ C, int N, int K, int m0, int n0,
                                          bf16* sm) {
  constexpr int WN = BN / 2, JN = WN / 16, NB = BN / 32;
  int tid = threadIdx.x, lane = tid & 63, w = tid >> 6;
  int quad = lane >> 4, l16 = lane & 15;
  int wm = (w >> 1) * 64, wn = (w & 1) * WN;
  int srow = lane >> 3;            // row-within-8-group staged by this lane
  int sG = (lane & 7) ^ srow;      // source granule for stored position lane&7

  bf16* Asb[2] = { sm, sm + 8192 };
  bf16* Bsb[2] = { sm + 16384, sm + 16384 + BN * 64 };

  const bf16* ga[4];
  const bf16* gb[NB];
#pragma unroll
  for (int j = 0; j < 4; j++) ga[j] = A + (long)(m0 + (4 * j + w) * 8 + srow) * K + sG * 8;
#pragma unroll
  for (int j = 0; j < NB; j++) gb[j] = Bt + (long)(n0 + (4 * j + w) * 8 + srow) * K + sG * 8;

  auto stage = [&](int b) {
#pragma unroll
    for (int j = 0; j < 4; j++) { dma16(ga[j], &Asb[b][(4 * j + w) * 512]); ga[j] += 64; }
#pragma unroll
    for (int j = 0; j < NB; j++) { dma16(gb[j], &Bsb[b][(4 * j + w) * 512]); gb[j] += 64; }
  };

  f32x4 acc[4][JN] = {};
  stage(0);
  asm volatile("" ::: "memory");
  int cur = 0;
  const int NK = K >> 6;
  for (int s = 0; s < NK; ++s) {
    if (s + 1 < NK) {
      stage(cur ^ 1);
      if constexpr (NB == 4) asm volatile("s_waitcnt vmcnt(8)" ::: "memory");
      else                   asm volatile("s_waitcnt vmcnt(6)" ::: "memory");
    } else {
      asm volatile("s_waitcnt vmcnt(0)" ::: "memory");
    }
    __builtin_amdgcn_s_barrier();      // tile s landed for all waves
    asm volatile("" ::: "memory");
    const bf16* Ac = Asb[cur];
    const bf16* Bc = Bsb[cur];
#pragma unroll
    for (int kk = 0; kk < 2; kk++) {
      bf16x8 af[4], bfr[JN];
#pragma unroll
      for (int i = 0; i < 4; i++) {
        int r = wm + i * 16 + l16;
        af[i] = *(const bf16x8*)&Ac[r * 64 + (((kk * 4 + quad) ^ r) & 7) * 8];
      }
#pragma unroll
      for (int j = 0; j < JN; j++) {
        int r = wn + j * 16 + l16;
        bfr[j] = *(const bf16x8*)&Bc[r * 64 + (((kk * 4 + quad) ^ r) & 7) * 8];
      }
#pragma unroll
      for (int i = 0; i < 4; i++)
#pragma unroll
        for (int j = 0; j < JN; j++)
          acc[i][j] = __builtin_amdgcn_mfma_f32_16x16x32_bf16(af[i], bfr[j], acc[i][j], 0, 0, 0);
    }
    asm volatile("" ::: "memory");
    __builtin_amdgcn_s_barrier();      // buf cur free for next stage's overwrite
    asm volatile("" ::: "memory");
    cur ^= 1;
  }

  if constexpr (MODE == 2) {
    bf16* tp = sm;  // [128][136] bf16 = 34.8 KB (sm is 64 KB)
#pragma unroll
    for (int i = 0; i < 4; i++)
#pragma unroll
      for (int j = 0; j < JN; j++)
#pragma unroll
        for (int r = 0; r < 4; r++)
          tp[(wn + j * 16 + l16) * 136 + wm + i * 16 + quad * 4 + r] = to_bf16(acc[i][j][r]);
    __syncthreads();
#pragma unroll
    for (int it = 0; it < 8; ++it) {
      int idx = it * 256 + tid;
      int rown = idx >> 4, c8 = (idx & 15) * 8;
      *(bf16x8*)&C[(size_t)(n0 + rown) * 4096 + m0 + c8] = *(const bf16x8*)&tp[rown * 136 + c8];
    }
  } else {
#pragma unroll
    for (int i = 0; i < 4; i++)
#pragma unroll
      for (int j = 0; j < JN; j++)
#pragma unroll
        for (int r = 0; r < 4; r++) {
          long row = m0 + wm + i * 16 + quad * 4 + r;
          long col = n0 + wn + j * 16 + l16;
          if constexpr (MODE == 0)
            C[row * N + col] = to_bf16(acc[i][j][r]);
          else
            C[row * N + col] = acc[i][j][r];
        }
  }
}

// merged q/k/v projections, exact 512-block grid; z==2 writes vT directly (transposed epilogue)
__global__ __launch_bounds__(256) void proj_gemm(const bf16* __restrict__ QKVb,
                                                 const bf16* __restrict__ Wt,
                                                 bf16* __restrict__ qkout,
                                                 bf16* __restrict__ vTout) {
  __shared__ __align__(16) bf16 sm[4 * 128 * 64];   // 64 KB
  int bid = blockIdx.x;
  if (bid < 256) {
    int z = bid >> 7;                 // 0:q 1:k
    int t = bid & 127;
    int m0 = (t & 31) * 128, n0 = (t >> 5) * 128;
    gemm_body<128, 0, bf16>(QKVb + (size_t)z * 2097152, Wt + (size_t)z * 262144,
                            qkout + (size_t)z * 2097152, 512, 512, m0, n0, sm);
  } else {
    int t = bid - 256;                // 0..255 -> v projection, 4096x1024
    int m0 = (t & 31) * 128, n0 = (t >> 5) * 128;
    gemm_body<128, 2, bf16>(QKVb + (size_t)2 * 2097152, Wt + (size_t)2 * 262144,
                            vTout, 1024, 512, m0, n0, sm);
  }
}

// output projection: 128x64 tiles -> 256 blocks
__global__ __launch_bounds__(256) void out_gemm(const bf16* __restrict__ xin,
                                                const bf16* __restrict__ Wob,
                                                float* __restrict__ outp) {
  __shared__ __align__(16) bf16 sm[2 * 128 * 64 + 2 * 64 * 64];   // 48 KB
  gemm_body<64, 1, float>(xin, Wob, outp, 512, 1024, blockIdx.x * 128, blockIdx.y * 64, sm);
}

// ---------------- fused attention (R10 schedule: best measured, 109.6 us / 211.0 total) ----------------
// qb,kb: [N][512]; vT: [1024][N]; x: [N][1024]
// Block = (head, dvh, q0): 64 q x 128 dv; 8 waves (cd,g); grid 512 = 2 blocks/CU (73.5 KB LDS).
// S runs ONE TILE AHEAD. Per iter: {load pf(t) -> regs; barrier; stage K(t+2),V(t+1);
// counted vmcnt; [S(t+1) MFMAs || PV(t) MFMAs] in one phase; exp(t+1)+pt-write; barrier}.
// 2 barriers/tile. __expf (R11: exp2f libm path regressed); no setprio (R11: regressed in
// lockstep regime). Buffer parity: kt read (t+1)%2 / written t%2; vt read t%2 / written
// (t+1)%2; pt reads drained (lgkmcnt 0 + barrier) before overwrite. vmcnt: steady 4,
// t=62 -> 2, t=63 -> 0.
__global__ __launch_bounds__(512, 4) void attn(const bf16* __restrict__ qb,
                                               const bf16* __restrict__ kb,
                                               const bf16* __restrict__ vT,
                                               bf16* __restrict__ x) {
  __shared__ __align__(16) bf16 kt[2][64 * 128];   // [key][dk] swizzled, 2x16 KB
  __shared__ __align__(16) bf16 vt[2][128 * 64];   // [dv-half][key] swizzled, 2x16 KB
  __shared__ __align__(16) bf16 pt[64 * 72];       // [q][key], padded (9 KB)
  __shared__ float Lrow[64];

  const int bid = blockIdx.x;                      // 512 blocks
  const int xcd = bid & 7;
  const int head = xcd & 3;                        // one (head,dvh) pair per XCD
  const int dvh = xcd >> 2;                        // dv half 0..1
  const int q0 = (bid >> 3) * 64;                  // 0..4032
  const int tid = threadIdx.x;
  const int lane = tid & 63, w = tid >> 6;
  const int quad = lane >> 4, l16 = lane & 15;
  const int cd = w & 3;   // S: 16-key col tile; PV: 32-dv group
  const int g = w >> 2;   // q half

  // all-ones B-fragment: B[n][k] = (n==0) -> D[q][0] = sum_k P[q][k]
  bf16x8 onesf;
  {
    union { bf16 h[8]; bf16x8 v; } u;
    bf16 one = to_bf16(1.0f), zero = to_bf16(0.0f);
#pragma unroll
    for (int j = 0; j < 8; j++) u.h[j] = (l16 == 0) ? one : zero;
    onesf = u.v;
  }

  // preload q fragments (A-layout: m=l16, k=quad*8+j)
  bf16x8 qf[2][4];
#pragma unroll
  for (int i = 0; i < 2; i++) {
    const bf16* qrow = &qb[(size_t)(q0 + g * 32 + i * 16 + l16) * 512 + head * 128];
#pragma unroll
    for (int kk = 0; kk < 4; kk++) qf[i][kk] = *(const bf16x8*)&qrow[kk * 32 + quad * 8];
  }

  f32x4 oacc[2][2] = {};
  f32x4 oL[2] = {};
  const float scale = 1.0f / 64.0f;  // 1/sqrt(4096)

  // DMA source pointers (advance per staged tile). kt: 16 j-groups (4 key-rows x 128 dk);
  // vt: 16 j-groups (8 dv-rows x 64 keys). j = 2w+t2.
  const int j0 = 2 * w, j1 = 2 * w + 1;
  const bf16 *kp0, *kp1, *vp0, *vp1;
  {
    int r0 = 4 * j0 + (lane >> 4), r1 = 4 * j1 + (lane >> 4);
    int p = lane & 15;
    int G0 = (p & 8) | ((p ^ r0) & 7), G1 = (p & 8) | ((p ^ r1) & 7);
    kp0 = kb + (size_t)r0 * 512 + head * 128 + G0 * 8;
    kp1 = kb + (size_t)r1 * 512 + head * 128 + G1 * 8;
  }
  {
    int r0 = 8 * j0 + (lane >> 3), r1 = 8 * j1 + (lane >> 3);
    int p = lane & 7;
    int G0 = (p ^ r0) & 7, G1 = (p ^ r1) & 7;
    vp0 = vT + (size_t)(head * 256 + dvh * 128 + r0) * 4096 + G0 * 8;
    vp1 = vT + (size_t)(head * 256 + dvh * 128 + r1) * 4096 + G1 * 8;
  }

#define STAGE_K(b)                                      \
  do {                                                  \
    dma16(kp0, &kt[b][j0 * 512]);                       \
    dma16(kp1, &kt[b][j1 * 512]);                       \
    kp0 += 64 * 512; kp1 += 64 * 512;                   \
  } while (0)
#define STAGE_V(b)                                      \
  do {                                                  \
    dma16(vp0, &vt[b][j0 * 512]);                       \
    dma16(vp1, &vt[b][j1 * 512]);                       \
    vp0 += 64; vp1 += 64;                               \
  } while (0)

  // ---- prologue: stage K(0),V(0),K(1); compute S(0) -> pt ----
  STAGE_K(0);
  STAGE_V(0);
  STAGE_K(1);
  asm volatile("s_waitcnt vmcnt(2)" ::: "memory");   // K(0), V(0) landed; K(1) in flight
  __builtin_amdgcn_s_barrier();
  asm volatile("" ::: "memory");
  {
    const bf16* ktc = kt[0];
    f32x4 sacc[2] = {};
#pragma unroll
    for (int kk = 0; kk < 4; kk++) {
      int R = cd * 16 + l16;
      int G = kk * 4 + quad;
      bf16x8 kf = *(const bf16x8*)&ktc[R * 128 + (((G ^ R) & 7) | (G & 8)) * 8];
      sacc[0] = __builtin_amdgcn_mfma_f32_16x16x32_bf16(qf[0][kk], kf, sacc[0], 0, 0, 0);
      sacc[1] = __builtin_amdgcn_mfma_f32_16x16x32_bf16(qf[1][kk], kf, sacc[1], 0, 0, 0);
    }
#pragma unroll
    for (int i = 0; i < 2; i++)
#pragma unroll
      for (int r = 0; r < 4; r++)
        pt[(g * 32 + i * 16 + quad * 4 + r) * 72 + cd * 16 + l16] =
            to_bf16(__expf(sacc[i][r] * scale));
  }
  asm volatile("s_waitcnt lgkmcnt(0)" ::: "memory");
  __builtin_amdgcn_s_barrier();                      // pt(0) ready
  asm volatile("" ::: "memory");

  for (int t = 0; t < 64; ++t) {
    // ---- load pf(t) into registers, then free pt for S(t+1) ----
    bf16x8 pf[2][2];
#pragma unroll
    for (int kk = 0; kk < 2; kk++)
#pragma unroll
      for (int i = 0; i < 2; i++)
        pf[kk][i] = *(const bf16x8*)&pt[(g * 32 + i * 16 + l16) * 72 + kk * 32 + quad * 8];
    asm volatile("s_waitcnt lgkmcnt(0)" ::: "memory");
    __builtin_amdgcn_s_barrier();        // all waves hold pf(t); pt free
    asm volatile("" ::: "memory");

    // ---- stage ahead: K(t+2) into buf t%2, V(t+1) into buf (t+1)%2 ----
    if (t < 62) STAGE_K(t & 1);
    if (t < 63) STAGE_V((t + 1) & 1);
    if (t < 62)      asm volatile("s_waitcnt vmcnt(4)" ::: "memory");  // K(t+1),V(t) landed
    else if (t == 62) asm volatile("s_waitcnt vmcnt(2)" ::: "memory");
    else              asm volatile("s_waitcnt vmcnt(0)" ::: "memory");

    // ---- merged phase: S(t+1) || PV(t) ----
    if (t < 63) {
      const bf16* ktc = kt[(t + 1) & 1];
      const bf16* vtc = vt[t & 1];
      f32x4 sacc[2] = {};
#pragma unroll
      for (int kk = 0; kk < 4; kk++) {
        int R = cd * 16 + l16;
        int G = kk * 4 + quad;
        bf16x8 kf = *(const bf16x8*)&ktc[R * 128 + (((G ^ R) & 7) | (G & 8)) * 8];
        sacc[0] = __builtin_amdgcn_mfma_f32_16x16x32_bf16(qf[0][kk], kf, sacc[0], 0, 0, 0);
        sacc[1] = __builtin_amdgcn_mfma_f32_16x16x32_bf16(qf[1][kk], kf, sacc[1], 0, 0, 0);
      }
#pragma unroll
      for (int kk = 0; kk < 2; kk++) {
#pragma unroll
        for (int c = 0; c < 2; c++) {
          int R = cd * 32 + c * 16 + l16;
          int G = kk * 4 + quad;
          bf16x8 vf = *(const bf16x8*)&vtc[R * 64 + ((G ^ R) & 7) * 8];
#pragma unroll
          for (int i = 0; i < 2; i++)
            oacc[i][c] = __builtin_amdgcn_mfma_f32_16x16x32_bf16(pf[kk][i], vf, oacc[i][c], 0, 0, 0);
        }
        if (cd == 3) {
#pragma unroll
          for (int i = 0; i < 2; i++)
            oL[i] = __builtin_amdgcn_mfma_f32_16x16x32_bf16(pf[kk][i], onesf, oL[i], 0, 0, 0);
        }
      }
      // exp(t+1) + pt write (trails the S MFMAs)
#pragma unroll
      for (int i = 0; i < 2; i++)
#pragma unroll
        for (int r = 0; r < 4; r++)
          pt[(g * 32 + i * 16 + quad * 4 + r) * 72 + cd * 16 + l16] =
              to_bf16(__expf(sacc[i][r] * scale));
    } else {
      // last iter: PV(63) only
      const bf16* vtc = vt[t & 1];
#pragma unroll
      for (int kk = 0; kk < 2; kk++) {
#pragma unroll
        for (int c = 0; c < 2; c++) {
          int R = cd * 32 + c * 16 + l16;
          int G = kk * 4 + quad;
          bf16x8 vf = *(const bf16x8*)&vtc[R * 64 + ((G ^ R) & 7) * 8];
#pragma unroll
          for (int i = 0; i < 2; i++)
            oacc[i][c] = __builtin_amdgcn_mfma_f32_16x16x32_bf16(pf[kk][i], vf, oacc[i][c], 0, 0, 0);
        }
        if (cd == 3) {
#pragma unroll
          for (int i = 0; i < 2; i++)
            oL[i] = __builtin_amdgcn_mfma_f32_16x16x32_bf16(pf[kk][i], onesf, oL[i], 0, 0, 0);
        }
      }
    }
    asm volatile("s_waitcnt lgkmcnt(0)" ::: "memory");   // pt(t+1) writes visible
    __builtin_amdgcn_s_barrier();        // pt(t+1) ready; buffers rotate
    asm volatile("" ::: "memory");
  }
#undef STAGE_K
#undef STAGE_V

  // L at lanes l16==0 of cd==3 waves (C-layout col 0)
  if (cd == 3 && l16 == 0) {
#pragma unroll
    for (int i = 0; i < 2; i++)
#pragma unroll
      for (int r = 0; r < 4; r++) Lrow[g * 32 + i * 16 + quad * 4 + r] = oL[i][r];
  }
  __syncthreads();

  // normalize + write x[n][head*256 + dvh*128 + dv]
#pragma unroll
  for (int i = 0; i < 2; i++)
#pragma unroll
    for (int c = 0; c < 2; c++)
#pragma unroll
      for (int r = 0; r < 4; r++) {
        int row = g * 32 + i * 16 + quad * 4 + r;
        float v = oacc[i][c][r] / Lrow[row];
        x[(size_t)(q0 + row) * 1024 + head * 256 + dvh * 128 + cd * 32 + c * 16 + l16] =
            to_bf16(v);
      }
}

// ---------------- launch ----------------
extern "C" void kernel_launch(void* const* d_in, const int* in_sizes, int n_in,
                              void* d_out, int out_size, void* d_ws, size_t ws_size,
                              hipStream_t stream) {
  const float* Q  = (const float*)d_in[0];
  const float* Km = (const float*)d_in[1];
  const float* V  = (const float*)d_in[2];
  const float* Wq = (const float*)d_in[3];
  const float* Wk = (const float*)d_in[4];
  const float* Wv = (const float*)d_in[5];
  const float* Wo = (const float*)d_in[6];
  float* out = (float*)d_out;

  bf16* ws  = (bf16*)d_ws;
  bf16* Qb  = ws;                 // 4096x512   (Qb,Kb,Vb contiguous)
  bf16* Kb  = Qb + 2097152;
  bf16* Vb  = Kb + 2097152;
  bf16* Wqt = Vb + 2097152;       // 512x512  (Wqt,Wkt,Wvt contiguous)
  bf16* Wkt = Wqt + 262144;
  bf16* Wvt = Wkt + 262144;       // 1024x512 (Bt)
  bf16* Wob = Wvt + 524288;       // 512x1024 (Bt = Wo as-is)
  bf16* qb  = Wob + 524288;       // 4096x512   (qb,kb contiguous)
  bf16* kb  = qb + 2097152;
  bf16* vT  = kb + 2097152;       // 1024x4096  (written directly by proj z==2)
  bf16* x   = vT + 4194304;       // 4096x1024

  prep<<<3712, 256, 0, stream>>>(Q, Km, V, Wo, Qb, Kb, Vb, Wob, Wq, Wk, Wv, Wqt, Wkt, Wvt);

  proj_gemm<<<512, 256, 0, stream>>>(Qb, Wqt, qb, vT);

  attn<<<512, 512, 0, stream>>>(qb, kb, vT, x);

  out_gemm<<<dim3(32, 8), 256, 0, stream>>>(x, Wob, out);
}